// Round 19
// baseline (547.167 us; speedup 1.0000x reference)
//
#include <hip/hip_runtime.h>
#include <math.h>

// ODE-RNN persistent kernel, round 30: head folded into main's tail.
// R29 post-mortem: wall 406 = main 228 + ~178 aux vs ~60us memory floor --
// the head dispatch (wl1p 800MB L2 re-stream + launch gap) dominates aux.
// Every main-WG already owns its 4 rows' full y history (wrote all 400
// slabs itself; zero cross-WG data), so the head runs as a TAIL inside
// odernn_main: threadfence+syncthreads (same-WG global write->read), then
// wave w covers mt-residue (w>>2) x n-group (w&3) of the 4x100 flattened
// output space (4-way A-reuse, same reduce shape as R29's head ->
// bit-identical absmax). Partials in LDS scratch aliasing the dead w1L;
// one barrier; 400 threads finalize. Separate head kernel deleted.
// Loop body byte-identical to proven R27/R29 main (228us). One change.

#define NWG  256
#define NTHR 1024
#define Tn   100
#define Dn   64
#define Hn   512
#define Fn   50
#define YP   528   // fp16 pitch
#define YQP  544   // i8 pitch
#define GPp  80
#define GPI  17
#define SB_WHH 2873.682f              // 127 / (1/sqrt(512))
#define QDH (1.0f/(125.0f*SB_WHH))    // dequant: (1/sA)*(1/sB)

// LDS-only barrier: orders LDS traffic, skips the vmcnt(0) global drain.
#define LDS_BAR() do { \
    asm volatile("s_waitcnt lgkmcnt(0)" ::: "memory"); \
    __builtin_amdgcn_s_barrier(); } while (0)

typedef __attribute__((ext_vector_type(8))) _Float16 half8;
typedef __attribute__((ext_vector_type(4))) float f32x4;
typedef __attribute__((ext_vector_type(4))) int   i32x4;

__device__ __forceinline__ float my_tanh(float v) {
    float e = __expf(2.0f * v);
    return 1.0f - 2.0f * __builtin_amdgcn_rcpf(e + 1.0f);   // exact 0 at v=0
}
__device__ __forceinline__ float wave_red(float v) {
#pragma unroll
    for (int o = 32; o > 0; o >>= 1) v += __shfl_down(v, o);
    return v;
}
__device__ __forceinline__ signed char q125(float v) {
    return (signed char)(int)rintf(v * 125.0f);
}
// constant-index select trees (per-lane q; no scratch, pure v_cndmask)
__device__ __forceinline__ float selq4(f32x4 v, int qq) {
    float a = (qq & 1) ? v[1] : v[0];
    float b = (qq & 1) ? v[3] : v[2];
    return (qq & 2) ? b : a;
}
__device__ __forceinline__ float selq4i(i32x4 v, int qq) {
    int a = (qq & 1) ? v[1] : v[0];
    int b = (qq & 1) ? v[3] : v[2];
    return (float)((qq & 2) ? b : a);
}

// f-net through GEMM2; returns RAW GEMM2 accumulators in c2[] (regs).
// Interior barriers are LDS-only (gp/gbf are pure LDS traffic).
__device__ __forceinline__ void feval_g2raw(
    const _Float16* arg, const half8* w1b, const half8* w2b,
    float* gp, _Float16* gbf, const float b1v,
    int w, int lane, int tid, int qq, f32x4 c2[2])
{
    const int m4 = lane & 3, cw = lane & 15;
    const int kh = w >> 2;
    f32x4 acc = {0.f, 0.f, 0.f, 0.f};
    const _Float16* arow = arg + m4 * YP + qq * 8;
#pragma unroll
    for (int t = 0; t < 4; ++t) {
        half8 a = *(const half8*)(arow + (kh * 4 + t) * 32);
        acc = __builtin_amdgcn_mfma_f32_16x16x32_f16(a, w1b[t * 64], acc, 0, 0, 0);
    }
    gp[(w * 4 + qq) * GPI + cw] = selq4(acc, qq);
    LDS_BAR();   // S3
    if (tid < 256) {   // mid layer once: 4 rows x 64 neurons (true K-reduce)
        const int r = tid >> 6, n = tid & 63;
        const int nt = n >> 4, c = n & 15;
        float s = gp[((0*4 + nt) * 4 + r) * GPI + c]
                + gp[((1*4 + nt) * 4 + r) * GPI + c]
                + gp[((2*4 + nt) * 4 + r) * GPI + c]
                + gp[((3*4 + nt) * 4 + r) * GPI + c];
        float g = (n < Fn) ? my_tanh(s + b1v) : 0.0f;
        gbf[r * GPp + n] = (_Float16)g;
    }
    LDS_BAR();   // S4
    half8 af0 = *(const half8*)(gbf + m4 * GPp + qq * 8);
    half8 af1 = *(const half8*)(gbf + m4 * GPp + 32 + qq * 8);
#pragma unroll
    for (int i = 0; i < 2; ++i) {
        f32x4 c = {0.f, 0.f, 0.f, 0.f};
        c = __builtin_amdgcn_mfma_f32_16x16x32_f16(af0, w2b[(i*2 + 0) * 64], c, 0, 0, 0);
        c = __builtin_amdgcn_mfma_f32_16x16x32_f16(af1, w2b[(i*2 + 1) * 64], c, 0, 0, 0);
        c2[i] = c;
    }
}

extern "C" __global__ void __launch_bounds__(NTHR, 4)
odernn_main(const float* __restrict__ b1,   const float* __restrict__ b2,
            const float* __restrict__ bl1,  const float* __restrict__ Wmu,
            const float* __restrict__ bmu,
            const _Float16* __restrict__ w1p,  const _Float16* __restrict__ w2p,
            const signed char* __restrict__ whh8,
            const _Float16* __restrict__ wl1p,
            _Float16* xwyg, const _Float16* __restrict__ scp,
            float* __restrict__ out, int defer)
{
    __shared__ __align__(16) _Float16 ybuf[4*YP];
    __shared__ __align__(16) signed char ybq[4*YQP];
    __shared__ __align__(16) _Float16 gbf[4*GPp];
    __shared__ __align__(16) float    gp[64*GPI];
    __shared__ float hp[64];
    __shared__ __align__(16) _Float16 w1L[16 * 4 * 64 * 8];   // 64 KB
    __shared__ __align__(16) _Float16 w2L[16 * 4 * 64 * 8];   // 64 KB

    const int tid  = threadIdx.x;
    const int w    = tid >> 6;       // wave 0..15
    const int lane = tid & 63;
    const int m4   = lane & 3, q = (lane >> 4) & 3;
    const int cw   = lane & 15;
    const int row0 = blockIdx.x * 4;

    for (int i = tid; i < 4*YP;  i += NTHR) ybuf[i] = (_Float16)0.0f;
    for (int i = tid; i < 4*YQP; i += NTHR) ybq[i]  = 0;

    // stage loop-invariant f-net fragments into LDS (once; R19-proven)
    {
        half8* w1d = ((half8*)w1L) + (w * 4) * 64 + lane;
        const int kh = w >> 2, nt1 = w & 3;
#pragma unroll
        for (int t = 0; t < 4; ++t) {
            const int kt = kh * 4 + t;
            w1d[t * 64] = ((const half8*)w1p)[(((kt << 2) + nt1) << 6) + lane];
        }
        half8* w2d = ((half8*)w2L) + (w * 4) * 64 + lane;
#pragma unroll
        for (int i = 0; i < 2; ++i) {
            const int nt = w + (i << 4);
            w2d[(i*2 + 0) * 64] = ((const half8*)w2p)[(nt << 6) + lane];
            w2d[(i*2 + 1) * 64] = ((const half8*)w2p)[((32 + nt) << 6) + lane];
        }
    }

    // ---- Whh int8 B-fragments -> AGPRs in ONE atomic asm block (R22-proven)
    i32x4 bq0,  bq1,  bq2,  bq3,  bq4,  bq5,  bq6,  bq7;
    i32x4 bq8,  bq9,  bq10, bq11, bq12, bq13, bq14, bq15;
#define WADDR(kt, ntadd) (whh8 + ((((kt)*32 + w + (ntadd)) << 10) + (lane << 4)))
    asm volatile(
        "global_load_dwordx4 %0, %16, off\n\t"
        "global_load_dwordx4 %1, %17, off\n\t"
        "global_load_dwordx4 %2, %18, off\n\t"
        "global_load_dwordx4 %3, %19, off\n\t"
        "global_load_dwordx4 %4, %20, off\n\t"
        "global_load_dwordx4 %5, %21, off\n\t"
        "global_load_dwordx4 %6, %22, off\n\t"
        "global_load_dwordx4 %7, %23, off\n\t"
        "global_load_dwordx4 %8, %24, off\n\t"
        "global_load_dwordx4 %9, %25, off\n\t"
        "global_load_dwordx4 %10, %26, off\n\t"
        "global_load_dwordx4 %11, %27, off\n\t"
        "global_load_dwordx4 %12, %28, off\n\t"
        "global_load_dwordx4 %13, %29, off\n\t"
        "global_load_dwordx4 %14, %30, off\n\t"
        "global_load_dwordx4 %15, %31, off\n\t"
        "s_waitcnt vmcnt(0)"
        : "=a"(bq0),  "=a"(bq1),  "=a"(bq2),  "=a"(bq3),
          "=a"(bq4),  "=a"(bq5),  "=a"(bq6),  "=a"(bq7),
          "=a"(bq8),  "=a"(bq9),  "=a"(bq10), "=a"(bq11),
          "=a"(bq12), "=a"(bq13), "=a"(bq14), "=a"(bq15)
        : "v"(WADDR(0,0)),  "v"(WADDR(0,16)),
          "v"(WADDR(1,0)),  "v"(WADDR(1,16)),
          "v"(WADDR(2,0)),  "v"(WADDR(2,16)),
          "v"(WADDR(3,0)),  "v"(WADDR(3,16)),
          "v"(WADDR(4,0)),  "v"(WADDR(4,16)),
          "v"(WADDR(5,0)),  "v"(WADDR(5,16)),
          "v"(WADDR(6,0)),  "v"(WADDR(6,16)),
          "v"(WADDR(7,0)),  "v"(WADDR(7,16))
        : "memory");
#undef WADDR

    float b2v[2];
    int ci[2];
#pragma unroll
    for (int i = 0; i < 2; ++i) {
        const int n = (w + i*16)*16 + cw;
        b2v[i] = b2[n];
        ci[i]  = n;
    }
    const float b1v = (tid < 256 && (tid & 63) < Fn) ? b1[tid & 63] : 0.0f;
    const float blv = bl1[w*16 + cw];   // fallback head only
    const float wmv = Wmu[w*16 + cw];
    const float bmu0 = bmu[0];

    const half8* w1b = ((const half8*)w1L) + (w * 4) * 64 + lane;
    const half8* w2b = ((const half8*)w2L) + (w * 4) * 64 + lane;

    // per-lane xw/sc streams: row (row0+q), cols ci0/ci1
    const size_t xrow = (size_t)(row0 + q) * Tn;
    _Float16 xwc0 = xwyg[(xrow + 0) * 512 + ci[0]];
    _Float16 xwc1 = xwyg[(xrow + 0) * 512 + ci[1]];
    float    scc  = (float)scp[xrow + 0];
    _Float16 xwn0, xwn1;
    float scn = 0.f;

    __syncthreads();

#pragma unroll 1
    for (int ts = 0; ts < Tn; ++ts) {
        // ---- Phase B: int8 MFMA (B from AGPRs) + diagonal dequant+tanh ----
        float ya, yb;
        {
            i32x4 accQ0 = {0,0,0,0};
            i32x4 accQ1 = {0,0,0,0};
            const signed char* yq = ybq + m4*YQP + q*16;
            i32x4 aq;
#define QMM(kt, B0, B1, PRE, POST) { \
            aq = *(const i32x4*)(yq + (kt)*64); \
            asm(PRE \
                "v_mfma_i32_16x16x64_i8 %0, %2, %3, %0\n\t" \
                "v_mfma_i32_16x16x64_i8 %1, %2, %4, %1" \
                POST \
                : "+v"(accQ0), "+v"(accQ1) \
                : "v"(aq), "a"(B0), "a"(B1)); }
            QMM(0, bq0,  bq1,  "s_nop 3\n\t", "")
            QMM(1, bq2,  bq3,  "", "")
            QMM(2, bq4,  bq5,  "", "")
            QMM(3, bq6,  bq7,  "", "")
            QMM(4, bq8,  bq9,  "", "")
            QMM(5, bq10, bq11, "", "")
            QMM(6, bq12, bq13, "", "")
            QMM(7, bq14, bq15, "", "\n\ts_nop 7\n\ts_nop 7\n\ts_nop 7")
#undef QMM
            ya = my_tanh(selq4i(accQ0, q) * QDH + (float)xwc0);
            yb = my_tanh(selq4i(accQ1, q) * QDH + (float)xwc1);
            ybuf[q*YP + ci[0]] = (_Float16)ya;
            ybuf[q*YP + ci[1]] = (_Float16)yb;
        }
        // prefetch xw/sc for next step (consumed next iteration -> full cover)
        {
            const int tsn = (ts + 1 < Tn) ? ts + 1 : ts;
            xwn0 = xwyg[(xrow + tsn) * 512 + ci[0]];
            xwn1 = xwyg[(xrow + tsn) * 512 + ci[1]];
            scn  = (float)scp[xrow + tsn];
        }
        LDS_BAR();   // S2: y0 in ybuf visible (LDS-only barrier)

        // ---- ODE f-eval through raw GEMM2 in regs (S3, S4 inside) ----
        f32x4 c2[2];
        feval_g2raw(ybuf, w1b, w2b, gp, gbf, b1v, w, lane, tid, q, c2);

        // ---- fused Euler + quant (diagonal, no barrier) ----
        _Float16 h0, h1;
        {
            float k0 = my_tanh(selq4(c2[0], q) + b2v[0]) * scc;
            float k1 = my_tanh(selq4(c2[1], q) + b2v[1]) * scc;
            float yn0 = ya + k0;
            float yn1 = yb + k1;
            h0 = (_Float16)yn0;
            h1 = (_Float16)yn1;
            ybuf[q*YP + ci[0]] = h0;
            ybuf[q*YP + ci[1]] = h1;
            ybq[q*YQP + ci[0]] = q125(yn0);
            ybq[q*YQP + ci[1]] = q125(yn1);
        }
        __syncthreads();   // S5: full drain (once per step)

        // h store AFTER S5 into the xw/yg buffer (slab (row,ts) already
        // consumed at this step) -- drains at next S5 with full cover
        if (defer) {
            xwyg[(xrow + ts) * 512 + ci[0]] = h0;
            xwyg[(xrow + ts) * 512 + ci[1]] = h1;
        } else {
            // in-loop head (fallback)
            f32x4 aH = {0.f,0.f,0.f,0.f};
            const _Float16* yh = ybuf + m4*YP + q*8;
#pragma unroll 4
            for (int kt = 0; kt < 16; ++kt) {
                half8 ah = *(const half8*)(yh + kt*32);
                half8 b = *(const half8*)(wl1p + ((kt*16 + w) << 9) + (lane << 3));
                aH = __builtin_amdgcn_mfma_f32_16x16x32_f16(ah, b, aH, 0,0,0);
            }
            float pr[4];
#pragma unroll
            for (int r = 0; r < 4; ++r) {
                float p = (lane < 16) ? fmaxf(aH[r] + blv, 0.0f) * wmv : 0.0f;
                pr[r] = wave_red(p);
            }
            if (lane == 0) {
#pragma unroll
                for (int r = 0; r < 4; ++r) hp[w*4 + r] = pr[r];
            }
            __syncthreads();
            if (tid < 4) {
                float s = bmu0;
#pragma unroll
                for (int wv = 0; wv < 16; ++wv) s += hp[wv*4 + tid];
                out[(size_t)(row0 + tid)*Tn + ts] = s;
            }
            __syncthreads();
        }
        xwc0 = xwn0; xwc1 = xwn1; scc = scn;
    }

    // ======== TAIL: head computed in-WG (defer path) ========
    // All 400 (row,ts) y-slabs were written by THIS WG; same-WG global
    // write->read needs threadfence + barrier only. Wave w: mt residue
    // g=w>>2 over 25 m-tiles of the flattened 4x100 output space,
    // n-group jn=w&3 (n-tiles jn*4..jn*4+3) -> 4-way A reuse (= R29 head).
    if (defer) {
        __threadfence();
        __syncthreads();
        float* scratch = (float*)w1L;          // w1L dead after the loop
        const int g  = w >> 2;
        const int jn = w & 3;
        const size_t abase = (size_t)row0 * Tn;
        // hoist per-j bias/weight (n = (jn*4+j)*16 + cw)
        float blvj[4], wmvj[4];
#pragma unroll
        for (int j = 0; j < 4; ++j) {
            const int n = (jn*4 + j)*16 + cw;
            blvj[j] = bl1[n];
            wmvj[j] = Wmu[n];
        }
#pragma unroll 1
        for (int mt = g; mt < 25; mt += 4) {
            f32x4 acc0 = {0.f,0.f,0.f,0.f};
            f32x4 acc1 = {0.f,0.f,0.f,0.f};
            f32x4 acc2 = {0.f,0.f,0.f,0.f};
            f32x4 acc3 = {0.f,0.f,0.f,0.f};
            const _Float16* ap = xwyg + (abase + mt*16 + cw) * 512 + q*8;
#pragma unroll 4
            for (int kt = 0; kt < 16; ++kt) {
                half8 a = *(const half8*)(ap + kt*32);
                const _Float16* bp = wl1p + ((kt*16 + jn*4) << 9) + (lane << 3);
                acc0 = __builtin_amdgcn_mfma_f32_16x16x32_f16(a, *(const half8*)(bp),          acc0, 0,0,0);
                acc1 = __builtin_amdgcn_mfma_f32_16x16x32_f16(a, *(const half8*)(bp + 512),    acc1, 0,0,0);
                acc2 = __builtin_amdgcn_mfma_f32_16x16x32_f16(a, *(const half8*)(bp + 1024),   acc2, 0,0,0);
                acc3 = __builtin_amdgcn_mfma_f32_16x16x32_f16(a, *(const half8*)(bp + 1536),   acc3, 0,0,0);
            }
            float pr[4];
#pragma unroll
            for (int r = 0; r < 4; ++r) {
                pr[r] = fmaxf(acc0[r] + blvj[0], 0.0f) * wmvj[0]
                      + fmaxf(acc1[r] + blvj[1], 0.0f) * wmvj[1]
                      + fmaxf(acc2[r] + blvj[2], 0.0f) * wmvj[2]
                      + fmaxf(acc3[r] + blvj[3], 0.0f) * wmvj[3];
#pragma unroll
                for (int o = 1; o < 16; o <<= 1) pr[r] += __shfl_xor(pr[r], o);
            }
            if (cw == 0) {
#pragma unroll
                for (int r = 0; r < 4; ++r)
                    scratch[(mt*4 + jn)*16 + q*4 + r] = pr[r];
            }
        }
        __syncthreads();
        if (tid < 400) {
            const int mt = tid >> 4, rr = tid & 15;
            float s = bmu0
                    + scratch[(mt*4 + 0)*16 + rr] + scratch[(mt*4 + 1)*16 + rr]
                    + scratch[(mt*4 + 2)*16 + rr] + scratch[(mt*4 + 3)*16 + rr];
            const int fl = mt*16 + rr;          // flattened row*100 + ts
            const int row = fl / Tn, ts2 = fl % Tn;
            out[(size_t)(row0 + row)*Tn + ts2] = s;
        }
    }
}

// one-shot precompute: xw[b][t][n] = x@Wih^T + b_ih + b_hh (fp16, into the
// yg buffer) and scp[b][t] = (dt1-dt0)*0.01 (fp16). Vectorized x loads.
extern "C" __global__ void __launch_bounds__(256, 4)
odernn_pre(const float* __restrict__ x, const float* __restrict__ dt,
           const float* __restrict__ b_ih, const float* __restrict__ b_hh,
           const _Float16* __restrict__ wih,
           _Float16* __restrict__ xw, _Float16* __restrict__ scp)
{
    const int tid = threadIdx.x, w = tid >> 6, lane = tid & 63;
    const int r16 = lane & 15, qq = lane >> 4;

    // dt scales (grid-stride over 102400 flattened (b,t))
    for (int p = blockIdx.x * 256 + tid; p < 1024 * Tn; p += gridDim.x * 256)
        scp[p] = (_Float16)((dt[p*2 + 1] - dt[p*2]) * 0.01f);

    const int g0 = blockIdx.x * 16;   // flattened row base (b*Tn + t)
    // A-fragments: rows g0+r16, K=64 (2 kt of 32); float4-vectorized loads
    const float* xb = x + (size_t)(g0 + r16) * 64 + qq * 8;
    f32x4 v0 = *(const f32x4*)(xb);
    f32x4 v1 = *(const f32x4*)(xb + 4);
    f32x4 v2 = *(const f32x4*)(xb + 32);
    f32x4 v3 = *(const f32x4*)(xb + 36);
    half8 a0, a1;
#pragma unroll
    for (int j = 0; j < 4; ++j) {
        a0[j]     = (_Float16)v0[j];
        a0[j + 4] = (_Float16)v1[j];
        a1[j]     = (_Float16)v2[j];
        a1[j + 4] = (_Float16)v3[j];
    }
    f32x4 acc[8];
#pragma unroll
    for (int i = 0; i < 8; ++i) acc[i] = (f32x4){0.f,0.f,0.f,0.f};
    const half8* wv = (const half8*)wih;
#pragma unroll
    for (int i = 0; i < 8; ++i) {
        const int nt = w*8 + i;
        acc[i] = __builtin_amdgcn_mfma_f32_16x16x32_f16(a0, wv[((0*32 + nt) << 6) + lane], acc[i], 0,0,0);
        acc[i] = __builtin_amdgcn_mfma_f32_16x16x32_f16(a1, wv[((1*32 + nt) << 6) + lane], acc[i], 0,0,0);
    }
#pragma unroll
    for (int i = 0; i < 8; ++i) {
        const int col = (w*8 + i)*16 + r16;
        const float bv = b_ih[col] + b_hh[col];
#pragma unroll
        for (int r = 0; r < 4; ++r)
            xw[(size_t)(g0 + qq*4 + r) * 512 + col] = (_Float16)(acc[i][r] + bv);
    }
}

// pack weights: fp16 MFMA B-fragment order (B[k][n] = W[n][k]) for the
// f-net / wih / wl1; int8 B-fragment order (K=64) for Whh.
extern "C" __global__ void odernn_init(
    const float* __restrict__ W_ih, const float* __restrict__ W_hh,
    const float* __restrict__ W1,   const float* __restrict__ W2,
    const float* __restrict__ Wl1,
    _Float16* w1p, _Float16* w2p, signed char* whh8, _Float16* wih,
    _Float16* wl1p)
{
    const int idx = blockIdx.x * blockDim.x + threadIdx.x;
    const int stride = gridDim.x * blockDim.x;
    // W1: KT=16, NT=4 (N 50->64), K=512
    for (int p = idx; p < 32768; p += stride) {
        int j = p & 7, lane = (p >> 3) & 63, t = p >> 9;
        int nt = t & 3, kt = t >> 2;
        int n = nt*16 + (lane & 15), k = kt*32 + ((lane >> 4) << 3) + j;
        w1p[p] = (_Float16)((n < 50) ? W1[n*512 + k] : 0.f);
    }
    // W2: KT=2 (K 50->64), NT=32, N=512
    for (int p = idx; p < 32768; p += stride) {
        int j = p & 7, lane = (p >> 3) & 63, t = p >> 9;
        int nt = t & 31, kt = t >> 5;
        int n = nt*16 + (lane & 15), k = kt*32 + ((lane >> 4) << 3) + j;
        w2p[p] = (_Float16)((k < 50) ? W2[n*50 + k] : 0.f);
    }
    // Whh int8: KT=8 (K=64 each), NT=32; B frag: 16 bytes/lane,
    // n = nt*16+(lane&15), k = kt*64 + (lane>>4)*16 + j
    for (int p = idx; p < 262144; p += stride) {
        int j = p & 15, lane = (p >> 4) & 63, t = p >> 10;
        int nt = t & 31, kt = t >> 5;
        int n = nt*16 + (lane & 15), k = kt*64 + ((lane >> 4) << 4) + j;
        float v = rintf(W_hh[n*512 + k] * SB_WHH);
        v = fminf(127.0f, fmaxf(-127.0f, v));
        whh8[p] = (signed char)(int)v;
    }
    // Wih: KT=2, NT=32, K=64 (fp16)
    for (int p = idx; p < 32768; p += stride) {
        int j = p & 7, lane = (p >> 3) & 63, t = p >> 9;
        int nt = t & 31, kt = t >> 5;
        int n = nt*16 + (lane & 15), k = kt*32 + ((lane >> 4) << 3) + j;
        wih[p] = (_Float16)W_ih[n*64 + k];
    }
    // Wl1: KT=16, NT=16, N=256, K=512
    for (int p = idx; p < 131072; p += stride) {
        int j = p & 7, lane = (p >> 3) & 63, t = p >> 9;
        int nt = t & 15, kt = t >> 4;
        int n = nt*16 + (lane & 15), k = kt*32 + ((lane >> 4) << 3) + j;
        wl1p[p] = (_Float16)Wl1[n*512 + k];
    }
}

extern "C" void kernel_launch(void* const* d_in, const int* in_sizes, int n_in,
                              void* d_out, int out_size, void* d_ws, size_t ws_size,
                              hipStream_t stream)
{
    (void)in_sizes; (void)n_in; (void)out_size;
    const float* dt   = (const float*)d_in[0];
    const float* x    = (const float*)d_in[1];
    const float* W_ih = (const float*)d_in[2];
    const float* b_ih = (const float*)d_in[3];
    const float* W_hh = (const float*)d_in[4];
    const float* b_hh = (const float*)d_in[5];
    const float* W1   = (const float*)d_in[6];
    const float* b1   = (const float*)d_in[7];
    const float* W2   = (const float*)d_in[8];
    const float* b2   = (const float*)d_in[9];
    const float* Wl1  = (const float*)d_in[10];
    const float* bl1  = (const float*)d_in[11];
    const float* Wmu  = (const float*)d_in[12];
    const float* bmu  = (const float*)d_in[13];
    float* out = (float*)d_out;

    char* ws = (char*)d_ws;
    _Float16*    w1p  = (_Float16*)(ws);             // 64 KB
    _Float16*    w2p  = (_Float16*)(ws + 65536);     // 64 KB
    signed char* whh8 = (signed char*)(ws + 131072); // 256 KB
    _Float16*    scp  = (_Float16*)(ws + 393216);    // 200 KB (whh slot tail)
    _Float16*    wih  = (_Float16*)(ws + 655360);    // 64 KB
    _Float16*    wl1p = (_Float16*)(ws + 720896);    // 256 KB
    _Float16*    xwyg = (_Float16*)(ws + 1048576);   // 105 MB: xw then yg

    const size_t need = 1048576 + (size_t)1024 * Tn * 512 * sizeof(_Float16);
    const int defer = (ws_size >= need) ? 1 : 0;

    odernn_init<<<256, 256, 0, stream>>>(W_ih, W_hh, W1, W2, Wl1,
                                         w1p, w2p, whh8, wih, wl1p);
    odernn_pre<<<(1024 * Tn) / 16, 256, 0, stream>>>(x, dt, b_ih, b_hh, wih,
                                                     xwyg, scp);
    odernn_main<<<NWG, NTHR, 0, stream>>>(b1, b2, bl1, Wmu, bmu,
                                          w1p, w2p, whh8, wl1p,
                                          xwyg, scp, out, defer);
}

// Round 20
// 398.714 us; speedup vs baseline: 1.3723x; 1.3723x over previous
//
#include <hip/hip_runtime.h>
#include <math.h>

// ODE-RNN persistent kernel, round 31: revert R30's tail fold; R29 + TSB=4.
// R30 post-mortem: folding the head into the persistent kernel made each
// of 256 WGs stream 6.4MB of wl1p (1.6GB L2 total, no cross-block
// amortization) in a serial tail: main 228->454us. The separate 
// head dispatch amortizes wl1p across thousands of blocks -- structurally
// right. R31 = exact R29 (proven wall 406: main 228 + aux) with ONE aux
// change: head TSB 2->4 (grid 1600, B-frag reuse 4x, wl1p 800->400MB).
// Reduce shape per output unchanged -> absmax exactly 0.001953125.
// Main/pre/init bodies byte-identical to R29.

#define NWG  256
#define NTHR 1024
#define Tn   100
#define Dn   64
#define Hn   512
#define Fn   50
#define TSB  4     // head timesteps per block
#define YP   528   // fp16 pitch
#define YQP  544   // i8 pitch
#define GPp  80
#define GPI  17
#define SB_WHH 2873.682f              // 127 / (1/sqrt(512))
#define QDH (1.0f/(125.0f*SB_WHH))    // dequant: (1/sA)*(1/sB)

// LDS-only barrier: orders LDS traffic, skips the vmcnt(0) global drain.
#define LDS_BAR() do { \
    asm volatile("s_waitcnt lgkmcnt(0)" ::: "memory"); \
    __builtin_amdgcn_s_barrier(); } while (0)

typedef __attribute__((ext_vector_type(8))) _Float16 half8;
typedef __attribute__((ext_vector_type(4))) float f32x4;
typedef __attribute__((ext_vector_type(4))) int   i32x4;

__device__ __forceinline__ float my_tanh(float v) {
    float e = __expf(2.0f * v);
    return 1.0f - 2.0f * __builtin_amdgcn_rcpf(e + 1.0f);   // exact 0 at v=0
}
__device__ __forceinline__ float wave_red(float v) {
#pragma unroll
    for (int o = 32; o > 0; o >>= 1) v += __shfl_down(v, o);
    return v;
}
__device__ __forceinline__ signed char q125(float v) {
    return (signed char)(int)rintf(v * 125.0f);
}
// constant-index select trees (per-lane q; no scratch, pure v_cndmask)
__device__ __forceinline__ float selq4(f32x4 v, int qq) {
    float a = (qq & 1) ? v[1] : v[0];
    float b = (qq & 1) ? v[3] : v[2];
    return (qq & 2) ? b : a;
}
__device__ __forceinline__ float selq4i(i32x4 v, int qq) {
    int a = (qq & 1) ? v[1] : v[0];
    int b = (qq & 1) ? v[3] : v[2];
    return (float)((qq & 2) ? b : a);
}

// f-net through GEMM2; returns RAW GEMM2 accumulators in c2[] (regs).
// Interior barriers are LDS-only (gp/gbf are pure LDS traffic).
__device__ __forceinline__ void feval_g2raw(
    const _Float16* arg, const half8* w1b, const half8* w2b,
    float* gp, _Float16* gbf, const float b1v,
    int w, int lane, int tid, int qq, f32x4 c2[2])
{
    const int m4 = lane & 3, cw = lane & 15;
    const int kh = w >> 2;
    f32x4 acc = {0.f, 0.f, 0.f, 0.f};
    const _Float16* arow = arg + m4 * YP + qq * 8;
#pragma unroll
    for (int t = 0; t < 4; ++t) {
        half8 a = *(const half8*)(arow + (kh * 4 + t) * 32);
        acc = __builtin_amdgcn_mfma_f32_16x16x32_f16(a, w1b[t * 64], acc, 0, 0, 0);
    }
    gp[(w * 4 + qq) * GPI + cw] = selq4(acc, qq);
    LDS_BAR();   // S3
    if (tid < 256) {   // mid layer once: 4 rows x 64 neurons (true K-reduce)
        const int r = tid >> 6, n = tid & 63;
        const int nt = n >> 4, c = n & 15;
        float s = gp[((0*4 + nt) * 4 + r) * GPI + c]
                + gp[((1*4 + nt) * 4 + r) * GPI + c]
                + gp[((2*4 + nt) * 4 + r) * GPI + c]
                + gp[((3*4 + nt) * 4 + r) * GPI + c];
        float g = (n < Fn) ? my_tanh(s + b1v) : 0.0f;
        gbf[r * GPp + n] = (_Float16)g;
    }
    LDS_BAR();   // S4
    half8 af0 = *(const half8*)(gbf + m4 * GPp + qq * 8);
    half8 af1 = *(const half8*)(gbf + m4 * GPp + 32 + qq * 8);
#pragma unroll
    for (int i = 0; i < 2; ++i) {
        f32x4 c = {0.f, 0.f, 0.f, 0.f};
        c = __builtin_amdgcn_mfma_f32_16x16x32_f16(af0, w2b[(i*2 + 0) * 64], c, 0, 0, 0);
        c = __builtin_amdgcn_mfma_f32_16x16x32_f16(af1, w2b[(i*2 + 1) * 64], c, 0, 0, 0);
        c2[i] = c;
    }
}

extern "C" __global__ void __launch_bounds__(NTHR, 4)
odernn_main(const float* __restrict__ b1,   const float* __restrict__ b2,
            const float* __restrict__ bl1,  const float* __restrict__ Wmu,
            const float* __restrict__ bmu,
            const _Float16* __restrict__ w1p,  const _Float16* __restrict__ w2p,
            const signed char* __restrict__ whh8,
            const _Float16* __restrict__ wl1p,
            _Float16* xwyg, const _Float16* __restrict__ scp,
            float* __restrict__ out, int defer)
{
    __shared__ __align__(16) _Float16 ybuf[4*YP];
    __shared__ __align__(16) signed char ybq[4*YQP];
    __shared__ __align__(16) _Float16 gbf[4*GPp];
    __shared__ __align__(16) float    gp[64*GPI];
    __shared__ float hp[64];
    __shared__ __align__(16) _Float16 w1L[16 * 4 * 64 * 8];   // 64 KB
    __shared__ __align__(16) _Float16 w2L[16 * 4 * 64 * 8];   // 64 KB

    const int tid  = threadIdx.x;
    const int w    = tid >> 6;       // wave 0..15
    const int lane = tid & 63;
    const int m4   = lane & 3, q = (lane >> 4) & 3;
    const int cw   = lane & 15;
    const int row0 = blockIdx.x * 4;

    for (int i = tid; i < 4*YP;  i += NTHR) ybuf[i] = (_Float16)0.0f;
    for (int i = tid; i < 4*YQP; i += NTHR) ybq[i]  = 0;

    // stage loop-invariant f-net fragments into LDS (once; R19-proven)
    {
        half8* w1d = ((half8*)w1L) + (w * 4) * 64 + lane;
        const int kh = w >> 2, nt1 = w & 3;
#pragma unroll
        for (int t = 0; t < 4; ++t) {
            const int kt = kh * 4 + t;
            w1d[t * 64] = ((const half8*)w1p)[(((kt << 2) + nt1) << 6) + lane];
        }
        half8* w2d = ((half8*)w2L) + (w * 4) * 64 + lane;
#pragma unroll
        for (int i = 0; i < 2; ++i) {
            const int nt = w + (i << 4);
            w2d[(i*2 + 0) * 64] = ((const half8*)w2p)[(nt << 6) + lane];
            w2d[(i*2 + 1) * 64] = ((const half8*)w2p)[((32 + nt) << 6) + lane];
        }
    }

    // ---- Whh int8 B-fragments -> AGPRs in ONE atomic asm block (R22-proven)
    i32x4 bq0,  bq1,  bq2,  bq3,  bq4,  bq5,  bq6,  bq7;
    i32x4 bq8,  bq9,  bq10, bq11, bq12, bq13, bq14, bq15;
#define WADDR(kt, ntadd) (whh8 + ((((kt)*32 + w + (ntadd)) << 10) + (lane << 4)))
    asm volatile(
        "global_load_dwordx4 %0, %16, off\n\t"
        "global_load_dwordx4 %1, %17, off\n\t"
        "global_load_dwordx4 %2, %18, off\n\t"
        "global_load_dwordx4 %3, %19, off\n\t"
        "global_load_dwordx4 %4, %20, off\n\t"
        "global_load_dwordx4 %5, %21, off\n\t"
        "global_load_dwordx4 %6, %22, off\n\t"
        "global_load_dwordx4 %7, %23, off\n\t"
        "global_load_dwordx4 %8, %24, off\n\t"
        "global_load_dwordx4 %9, %25, off\n\t"
        "global_load_dwordx4 %10, %26, off\n\t"
        "global_load_dwordx4 %11, %27, off\n\t"
        "global_load_dwordx4 %12, %28, off\n\t"
        "global_load_dwordx4 %13, %29, off\n\t"
        "global_load_dwordx4 %14, %30, off\n\t"
        "global_load_dwordx4 %15, %31, off\n\t"
        "s_waitcnt vmcnt(0)"
        : "=a"(bq0),  "=a"(bq1),  "=a"(bq2),  "=a"(bq3),
          "=a"(bq4),  "=a"(bq5),  "=a"(bq6),  "=a"(bq7),
          "=a"(bq8),  "=a"(bq9),  "=a"(bq10), "=a"(bq11),
          "=a"(bq12), "=a"(bq13), "=a"(bq14), "=a"(bq15)
        : "v"(WADDR(0,0)),  "v"(WADDR(0,16)),
          "v"(WADDR(1,0)),  "v"(WADDR(1,16)),
          "v"(WADDR(2,0)),  "v"(WADDR(2,16)),
          "v"(WADDR(3,0)),  "v"(WADDR(3,16)),
          "v"(WADDR(4,0)),  "v"(WADDR(4,16)),
          "v"(WADDR(5,0)),  "v"(WADDR(5,16)),
          "v"(WADDR(6,0)),  "v"(WADDR(6,16)),
          "v"(WADDR(7,0)),  "v"(WADDR(7,16))
        : "memory");
#undef WADDR

    float b2v[2];
    int ci[2];
#pragma unroll
    for (int i = 0; i < 2; ++i) {
        const int n = (w + i*16)*16 + cw;
        b2v[i] = b2[n];
        ci[i]  = n;
    }
    const float b1v = (tid < 256 && (tid & 63) < Fn) ? b1[tid & 63] : 0.0f;
    const float blv = bl1[w*16 + cw];   // fallback head only
    const float wmv = Wmu[w*16 + cw];
    const float bmu0 = bmu[0];

    const half8* w1b = ((const half8*)w1L) + (w * 4) * 64 + lane;
    const half8* w2b = ((const half8*)w2L) + (w * 4) * 64 + lane;

    // per-lane xw/sc streams: row (row0+q), cols ci0/ci1
    const size_t xrow = (size_t)(row0 + q) * Tn;
    _Float16 xwc0 = xwyg[(xrow + 0) * 512 + ci[0]];
    _Float16 xwc1 = xwyg[(xrow + 0) * 512 + ci[1]];
    float    scc  = (float)scp[xrow + 0];
    _Float16 xwn0, xwn1;
    float scn = 0.f;

    __syncthreads();

#pragma unroll 1
    for (int ts = 0; ts < Tn; ++ts) {
        // ---- Phase B: int8 MFMA (B from AGPRs) + diagonal dequant+tanh ----
        float ya, yb;
        {
            i32x4 accQ0 = {0,0,0,0};
            i32x4 accQ1 = {0,0,0,0};
            const signed char* yq = ybq + m4*YQP + q*16;
            i32x4 aq;
#define QMM(kt, B0, B1, PRE, POST) { \
            aq = *(const i32x4*)(yq + (kt)*64); \
            asm(PRE \
                "v_mfma_i32_16x16x64_i8 %0, %2, %3, %0\n\t" \
                "v_mfma_i32_16x16x64_i8 %1, %2, %4, %1" \
                POST \
                : "+v"(accQ0), "+v"(accQ1) \
                : "v"(aq), "a"(B0), "a"(B1)); }
            QMM(0, bq0,  bq1,  "s_nop 3\n\t", "")
            QMM(1, bq2,  bq3,  "", "")
            QMM(2, bq4,  bq5,  "", "")
            QMM(3, bq6,  bq7,  "", "")
            QMM(4, bq8,  bq9,  "", "")
            QMM(5, bq10, bq11, "", "")
            QMM(6, bq12, bq13, "", "")
            QMM(7, bq14, bq15, "", "\n\ts_nop 7\n\ts_nop 7\n\ts_nop 7")
#undef QMM
            ya = my_tanh(selq4i(accQ0, q) * QDH + (float)xwc0);
            yb = my_tanh(selq4i(accQ1, q) * QDH + (float)xwc1);
            ybuf[q*YP + ci[0]] = (_Float16)ya;
            ybuf[q*YP + ci[1]] = (_Float16)yb;
        }
        // prefetch xw/sc for next step (consumed next iteration -> full cover)
        {
            const int tsn = (ts + 1 < Tn) ? ts + 1 : ts;
            xwn0 = xwyg[(xrow + tsn) * 512 + ci[0]];
            xwn1 = xwyg[(xrow + tsn) * 512 + ci[1]];
            scn  = (float)scp[xrow + tsn];
        }
        LDS_BAR();   // S2: y0 in ybuf visible (LDS-only barrier)

        // ---- ODE f-eval through raw GEMM2 in regs (S3, S4 inside) ----
        f32x4 c2[2];
        feval_g2raw(ybuf, w1b, w2b, gp, gbf, b1v, w, lane, tid, q, c2);

        // ---- fused Euler + quant (diagonal, no barrier) ----
        _Float16 h0, h1;
        {
            float k0 = my_tanh(selq4(c2[0], q) + b2v[0]) * scc;
            float k1 = my_tanh(selq4(c2[1], q) + b2v[1]) * scc;
            float yn0 = ya + k0;
            float yn1 = yb + k1;
            h0 = (_Float16)yn0;
            h1 = (_Float16)yn1;
            ybuf[q*YP + ci[0]] = h0;
            ybuf[q*YP + ci[1]] = h1;
            ybq[q*YQP + ci[0]] = q125(yn0);
            ybq[q*YQP + ci[1]] = q125(yn1);
        }
        __syncthreads();   // S5: full drain (once per step)

        // h store AFTER S5 into the xw/yg buffer (slab (row,ts) already
        // consumed at this step) -- drains at next S5 with full cover
        if (defer) {
            xwyg[(xrow + ts) * 512 + ci[0]] = h0;
            xwyg[(xrow + ts) * 512 + ci[1]] = h1;
        } else {
            // in-loop head (fallback)
            f32x4 aH = {0.f,0.f,0.f,0.f};
            const _Float16* yh = ybuf + m4*YP + q*8;
#pragma unroll 4
            for (int kt = 0; kt < 16; ++kt) {
                half8 ah = *(const half8*)(yh + kt*32);
                half8 b = *(const half8*)(wl1p + ((kt*16 + w) << 9) + (lane << 3));
                aH = __builtin_amdgcn_mfma_f32_16x16x32_f16(ah, b, aH, 0,0,0);
            }
            float pr[4];
#pragma unroll
            for (int r = 0; r < 4; ++r) {
                float p = (lane < 16) ? fmaxf(aH[r] + blv, 0.0f) * wmv : 0.0f;
                pr[r] = wave_red(p);
            }
            if (lane == 0) {
#pragma unroll
                for (int r = 0; r < 4; ++r) hp[w*4 + r] = pr[r];
            }
            __syncthreads();
            if (tid < 4) {
                float s = bmu0;
#pragma unroll
                for (int wv = 0; wv < 16; ++wv) s += hp[wv*4 + tid];
                out[(size_t)(row0 + tid)*Tn + ts] = s;
            }
            __syncthreads();
        }
        xwc0 = xwn0; xwc1 = xwn1; scc = scn;
    }
}

// one-shot precompute: xw[b][t][n] = x@Wih^T + b_ih + b_hh (fp16, into the
// yg buffer) and scp[b][t] = (dt1-dt0)*0.01 (fp16). Vectorized x loads.
extern "C" __global__ void __launch_bounds__(256, 4)
odernn_pre(const float* __restrict__ x, const float* __restrict__ dt,
           const float* __restrict__ b_ih, const float* __restrict__ b_hh,
           const _Float16* __restrict__ wih,
           _Float16* __restrict__ xw, _Float16* __restrict__ scp)
{
    const int tid = threadIdx.x, w = tid >> 6, lane = tid & 63;
    const int r16 = lane & 15, qq = lane >> 4;

    // dt scales (grid-stride over 102400 flattened (b,t))
    for (int p = blockIdx.x * 256 + tid; p < 1024 * Tn; p += gridDim.x * 256)
        scp[p] = (_Float16)((dt[p*2 + 1] - dt[p*2]) * 0.01f);

    const int g0 = blockIdx.x * 16;   // flattened row base (b*Tn + t)
    // A-fragments: rows g0+r16, K=64 (2 kt of 32); float4-vectorized loads
    const float* xb = x + (size_t)(g0 + r16) * 64 + qq * 8;
    f32x4 v0 = *(const f32x4*)(xb);
    f32x4 v1 = *(const f32x4*)(xb + 4);
    f32x4 v2 = *(const f32x4*)(xb + 32);
    f32x4 v3 = *(const f32x4*)(xb + 36);
    half8 a0, a1;
#pragma unroll
    for (int j = 0; j < 4; ++j) {
        a0[j]     = (_Float16)v0[j];
        a0[j + 4] = (_Float16)v1[j];
        a1[j]     = (_Float16)v2[j];
        a1[j + 4] = (_Float16)v3[j];
    }
    f32x4 acc[8];
#pragma unroll
    for (int i = 0; i < 8; ++i) acc[i] = (f32x4){0.f,0.f,0.f,0.f};
    const half8* wv = (const half8*)wih;
#pragma unroll
    for (int i = 0; i < 8; ++i) {
        const int nt = w*8 + i;
        acc[i] = __builtin_amdgcn_mfma_f32_16x16x32_f16(a0, wv[((0*32 + nt) << 6) + lane], acc[i], 0,0,0);
        acc[i] = __builtin_amdgcn_mfma_f32_16x16x32_f16(a1, wv[((1*32 + nt) << 6) + lane], acc[i], 0,0,0);
    }
#pragma unroll
    for (int i = 0; i < 8; ++i) {
        const int col = (w*8 + i)*16 + r16;
        const float bv = b_ih[col] + b_hh[col];
#pragma unroll
        for (int r = 0; r < 4; ++r)
            xw[(size_t)(g0 + qq*4 + r) * 512 + col] = (_Float16)(acc[i][r] + bv);
    }
}

// phase-2 head: out[b,t] = relu(y[b,t]@Wl1^T + bl1)@Wmu^T + bmu
// grid = (B/16)*(Tn/TSB) WGs x 256 threads; each block covers TSB timesteps
// (B-fragments loaded once per (kt,j), reused across TSB -> wl1p L2 / TSB).
extern "C" __global__ void __launch_bounds__(256, 4)
odernn_head(const _Float16* __restrict__ yg, const _Float16* __restrict__ wl1p,
            const float* __restrict__ bl1, const float* __restrict__ Wmu,
            const float* __restrict__ bmu, float* __restrict__ out)
{
    __shared__ float hp[TSB][4][16];
    const int tid = threadIdx.x, w = tid >> 6, lane = tid & 63;
    const int q = (lane >> 4) & 3;
    const int nblk = Tn / TSB;                 // 25
    const int b0  = (blockIdx.x / nblk) * 16;
    const int ts0 = (blockIdx.x % nblk) * TSB;

    f32x4 acc[TSB][4];
#pragma unroll
    for (int t = 0; t < TSB; ++t)
#pragma unroll
        for (int j = 0; j < 4; ++j) acc[t][j] = (f32x4){0.f,0.f,0.f,0.f};
    const _Float16* ap = yg + ((size_t)(b0 + (lane & 15))*Tn + ts0)*512 + q*8;
#pragma unroll 4
    for (int kt = 0; kt < 16; ++kt) {
        half8 av[TSB];
#pragma unroll
        for (int t = 0; t < TSB; ++t)
            av[t] = *(const half8*)(ap + t*512 + kt*32);
#pragma unroll
        for (int j = 0; j < 4; ++j) {
            half8 b = *(const half8*)(wl1p + ((kt*16 + w*4 + j) << 9) + (lane << 3));
#pragma unroll
            for (int t = 0; t < TSB; ++t)
                acc[t][j] = __builtin_amdgcn_mfma_f32_16x16x32_f16(av[t], b, acc[t][j], 0,0,0);
        }
    }
#pragma unroll
    for (int t = 0; t < TSB; ++t) {
        float pr[4] = {0.f, 0.f, 0.f, 0.f};
#pragma unroll
        for (int j = 0; j < 4; ++j) {
            const int n = (w*4 + j)*16 + (lane & 15);
            const float blv = bl1[n], wmv = Wmu[n];
#pragma unroll
            for (int r = 0; r < 4; ++r)
                pr[r] += fmaxf(acc[t][j][r] + blv, 0.0f) * wmv;
        }
#pragma unroll
        for (int r = 0; r < 4; ++r)
#pragma unroll
            for (int o = 1; o < 16; o <<= 1) pr[r] += __shfl_xor(pr[r], o);
        if ((lane & 15) == 0) {
            const int g = lane >> 4;
#pragma unroll
            for (int r = 0; r < 4; ++r) hp[t][w][g*4 + r] = pr[r];
        }
    }
    __syncthreads();
    if (tid < 16 * TSB) {
        const int t = tid >> 4, rr = tid & 15;
        out[(size_t)(b0 + rr)*Tn + ts0 + t] =
            hp[t][0][rr] + hp[t][1][rr] + hp[t][2][rr] + hp[t][3][rr] + bmu[0];
    }
}

// pack weights: fp16 MFMA B-fragment order (B[k][n] = W[n][k]) for the
// f-net / wih / wl1; int8 B-fragment order (K=64) for Whh.
extern "C" __global__ void odernn_init(
    const float* __restrict__ W_ih, const float* __restrict__ W_hh,
    const float* __restrict__ W1,   const float* __restrict__ W2,
    const float* __restrict__ Wl1,
    _Float16* w1p, _Float16* w2p, signed char* whh8, _Float16* wih,
    _Float16* wl1p)
{
    const int idx = blockIdx.x * blockDim.x + threadIdx.x;
    const int stride = gridDim.x * blockDim.x;
    // W1: KT=16, NT=4 (N 50->64), K=512
    for (int p = idx; p < 32768; p += stride) {
        int j = p & 7, lane = (p >> 3) & 63, t = p >> 9;
        int nt = t & 3, kt = t >> 2;
        int n = nt*16 + (lane & 15), k = kt*32 + ((lane >> 4) << 3) + j;
        w1p[p] = (_Float16)((n < 50) ? W1[n*512 + k] : 0.f);
    }
    // W2: KT=2 (K 50->64), NT=32, N=512
    for (int p = idx; p < 32768; p += stride) {
        int j = p & 7, lane = (p >> 3) & 63, t = p >> 9;
        int nt = t & 31, kt = t >> 5;
        int n = nt*16 + (lane & 15), k = kt*32 + ((lane >> 4) << 3) + j;
        w2p[p] = (_Float16)((k < 50) ? W2[n*50 + k] : 0.f);
    }
    // Whh int8: KT=8 (K=64 each), NT=32; B frag: 16 bytes/lane,
    // n = nt*16+(lane&15), k = kt*64 + (lane>>4)*16 + j
    for (int p = idx; p < 262144; p += stride) {
        int j = p & 15, lane = (p >> 4) & 63, t = p >> 10;
        int nt = t & 31, kt = t >> 5;
        int n = nt*16 + (lane & 15), k = kt*64 + ((lane >> 4) << 4) + j;
        float v = rintf(W_hh[n*512 + k] * SB_WHH);
        v = fminf(127.0f, fmaxf(-127.0f, v));
        whh8[p] = (signed char)(int)v;
    }
    // Wih: KT=2, NT=32, K=64 (fp16)
    for (int p = idx; p < 32768; p += stride) {
        int j = p & 7, lane = (p >> 3) & 63, t = p >> 9;
        int nt = t & 31, kt = t >> 5;
        int n = nt*16 + (lane & 15), k = kt*32 + ((lane >> 4) << 3) + j;
        wih[p] = (_Float16)W_ih[n*64 + k];
    }
    // Wl1: KT=16, NT=16, N=256, K=512
    for (int p = idx; p < 131072; p += stride) {
        int j = p & 7, lane = (p >> 3) & 63, t = p >> 9;
        int nt = t & 15, kt = t >> 4;
        int n = nt*16 + (lane & 15), k = kt*32 + ((lane >> 4) << 3) + j;
        wl1p[p] = (_Float16)Wl1[n*512 + k];
    }
}

extern "C" void kernel_launch(void* const* d_in, const int* in_sizes, int n_in,
                              void* d_out, int out_size, void* d_ws, size_t ws_size,
                              hipStream_t stream)
{
    (void)in_sizes; (void)n_in; (void)out_size;
    const float* dt   = (const float*)d_in[0];
    const float* x    = (const float*)d_in[1];
    const float* W_ih = (const float*)d_in[2];
    const float* b_ih = (const float*)d_in[3];
    const float* W_hh = (const float*)d_in[4];
    const float* b_hh = (const float*)d_in[5];
    const float* W1   = (const float*)d_in[6];
    const float* b1   = (const float*)d_in[7];
    const float* W2   = (const float*)d_in[8];
    const float* b2   = (const float*)d_in[9];
    const float* Wl1  = (const float*)d_in[10];
    const float* bl1  = (const float*)d_in[11];
    const float* Wmu  = (const float*)d_in[12];
    const float* bmu  = (const float*)d_in[13];
    float* out = (float*)d_out;

    char* ws = (char*)d_ws;
    _Float16*    w1p  = (_Float16*)(ws);             // 64 KB
    _Float16*    w2p  = (_Float16*)(ws + 65536);     // 64 KB
    signed char* whh8 = (signed char*)(ws + 131072); // 256 KB
    _Float16*    scp  = (_Float16*)(ws + 393216);    // 200 KB (whh slot tail)
    _Float16*    wih  = (_Float16*)(ws + 655360);    // 64 KB
    _Float16*    wl1p = (_Float16*)(ws + 720896);    // 256 KB
    _Float16*    xwyg = (_Float16*)(ws + 1048576);   // 105 MB: xw then yg

    const size_t need = 1048576 + (size_t)1024 * Tn * 512 * sizeof(_Float16);
    const int defer = (ws_size >= need) ? 1 : 0;

    odernn_init<<<256, 256, 0, stream>>>(W_ih, W_hh, W1, W2, Wl1,
                                         w1p, w2p, whh8, wih, wl1p);
    odernn_pre<<<(1024 * Tn) / 16, 256, 0, stream>>>(x, dt, b_ih, b_hh, wih,
                                                     xwyg, scp);
    odernn_main<<<NWG, NTHR, 0, stream>>>(b1, b2, bl1, Wmu, bmu,
                                          w1p, w2p, whh8, wl1p,
                                          xwyg, scp, out, defer);
    if (defer)
        odernn_head<<<(1024/16)*(Tn/TSB), 256, 0, stream>>>(xwyg, wl1p, bl1,
                                                            Wmu, bmu, out);
}